// Round 1
// baseline (715.891 us; speedup 1.0000x reference)
//
#include <hip/hip_runtime.h>

typedef __bf16 bf16;
typedef __bf16 bf16x8 __attribute__((ext_vector_type(8)));
typedef float  f32x4  __attribute__((ext_vector_type(4)));

#define NSP 4096   // h*w
#define NCH 256    // channels
#define NB  8      // batch

// ---- wave helpers: reduce across the 16 lanes sharing (lane>>4) ----------
static __device__ __forceinline__ float red16_max(float v) {
  v = fmaxf(v, __shfl_xor(v, 1));
  v = fmaxf(v, __shfl_xor(v, 2));
  v = fmaxf(v, __shfl_xor(v, 4));
  v = fmaxf(v, __shfl_xor(v, 8));
  return v;
}
static __device__ __forceinline__ float red16_sum(float v) {
  v += __shfl_xor(v, 1);
  v += __shfl_xor(v, 2);
  v += __shfl_xor(v, 4);
  v += __shfl_xor(v, 8);
  return v;
}
// broadcast a row-indexed quantity (rows qd*4+r, uniform across the 16 lanes
// of a quad after red16) to column-indexed lanes (index = lane&15)
static __device__ __forceinline__ float row2col(const float a[4], int li) {
  int src = (li >> 2) << 4;            // any lane in quad (li>>2)
  float t0 = __shfl(a[0], src);
  float t1 = __shfl(a[1], src);
  float t2 = __shfl(a[2], src);
  float t3 = __shfl(a[3], src);
  int r = li & 3;
  return (r == 0) ? t0 : (r == 1) ? t1 : (r == 2) ? t2 : t3;
}

// ---------------- k0: weights fp32 -> bf16 (wq,bq get 1/sqrt(c)=1/16) -----
__global__ __launch_bounds__(256) void k_wconv(
    const float* __restrict__ wq, const float* __restrict__ wk,
    const float* __restrict__ wv, const float* __restrict__ wo,
    bf16* __restrict__ wbf) {
  int g = blockIdx.x * 256 + threadIdx.x;      // 0..262143
  int m = g >> 16, idx = g & 65535;
  const float* src = (m == 0) ? wq : (m == 1) ? wk : (m == 2) ? wv : wo;
  float sc = (m == 0) ? 0.0625f : 1.0f;
  wbf[g] = (bf16)(src[idx] * sc);
}

// ---------------- k1: groupnorm stats per (b,g): 131072 contiguous floats -
__global__ __launch_bounds__(256) void k_gnstats(const float* __restrict__ x,
                                                 float* __restrict__ stats) {
  int bg = blockIdx.x;                          // 64
  const float4* p = (const float4*)(x + (size_t)bg * 131072);
  float s = 0.f, s2 = 0.f;
  for (int i = threadIdx.x; i < 32768; i += 256) {
    float4 v = p[i];
    s  += v.x + v.y + v.z + v.w;
    s2 += v.x*v.x + v.y*v.y + v.z*v.z + v.w*v.w;
  }
  for (int off = 1; off < 64; off <<= 1) {
    s  += __shfl_xor(s, off);
    s2 += __shfl_xor(s2, off);
  }
  __shared__ float a1[4], a2[4];
  int w = threadIdx.x >> 6, lane = threadIdx.x & 63;
  if (lane == 0) { a1[w] = s; a2[w] = s2; }
  __syncthreads();
  if (threadIdx.x == 0) {
    float S  = a1[0] + a1[1] + a1[2] + a1[3];
    float S2 = a2[0] + a2[1] + a2[2] + a2[3];
    float mean = S * (1.f / 131072.f);
    float var  = S2 * (1.f / 131072.f) - mean * mean;
    stats[bg * 2]     = mean;
    stats[bg * 2 + 1] = rsqrtf(var + 1e-6f);
  }
}

// ---------------- k2: GN apply + transpose -> hnT[b][n][c] bf16 -----------
__global__ __launch_bounds__(256) void k_gnapply(const float* __restrict__ x,
    const float* __restrict__ stats, const float* __restrict__ gsc,
    const float* __restrict__ gbi, bf16* __restrict__ hnT) {
  __shared__ float T[64][65];                   // +1 pad: conflict-free
  int blk = blockIdx.x;                         // 8 * 4 * 64 = 2048
  int b = blk >> 8, ct = (blk >> 6) & 3, it = blk & 63;
  int tid = threadIdx.x;
  #pragma unroll 4
  for (int p = 0; p < 16; ++p) {
    int cc = p * 4 + (tid >> 6), ii = tid & 63;
    int c = ct * 64 + cc;
    float mean = stats[(b * 8 + (c >> 5)) * 2];
    float rstd = stats[(b * 8 + (c >> 5)) * 2 + 1];
    float v = x[((size_t)b * NCH + c) * NSP + it * 64 + ii];
    T[cc][ii] = (v - mean) * rstd * gsc[c] + gbi[c];
  }
  __syncthreads();
  #pragma unroll 4
  for (int p = 0; p < 16; ++p) {
    int ii = p * 4 + (tid >> 6), cc = tid & 63;
    hnT[((size_t)b * NSP + it * 64 + ii) * NCH + ct * 64 + cc] = (bf16)T[cc][ii];
  }
}

// ---------------- k3: fused QKV projection ---------------------------------
// qT[b][n][c], kT[b][n][c] (bf16), vM[b][c][n] (bf16). scale folded into wq/bq.
// MFMA: q/k: D[m=i][n=co] with A=hnT rows, B=W rows (B[k][n]=W[n][k], contiguous).
//       v:   D[m=co][n=i] with A=W rows, B=hnT rows.
__global__ __launch_bounds__(256) void k_qkv(const bf16* __restrict__ hnT,
    const bf16* __restrict__ wbf, const float* __restrict__ bq,
    const float* __restrict__ bk, const float* __restrict__ bv,
    bf16* __restrict__ qT, bf16* __restrict__ kT, bf16* __restrict__ vM) {
  const int b  = blockIdx.x >> 6;
  const int i0 = (blockIdx.x & 63) * 64;
  const int tid = threadIdx.x, w = tid >> 6, lane = tid & 63;
  const int li = lane & 15, qd = lane >> 4;

  // A-frags: this wave's 16 rows of hnT (i = i0 + w*16 + li)
  const bf16* hw = hnT + ((size_t)b * NSP + i0 + w * 16 + li) * NCH + qd * 8;
  bf16x8 hf[8];
  #pragma unroll
  for (int kc = 0; kc < 8; ++kc) hf[kc] = *(const bf16x8*)(hw + kc * 32);

  #pragma unroll 1
  for (int pass = 0; pass < 2; ++pass) {        // 0: q, 1: k
    const bf16* W = wbf + (size_t)pass * 65536;
    const float* bias = pass ? bk : bq;
    const float bsc = pass ? 1.0f : 0.0625f;
    f32x4 acc[16];
    #pragma unroll
    for (int t = 0; t < 16; ++t) acc[t] = (f32x4){0.f, 0.f, 0.f, 0.f};
    for (int kc = 0; kc < 8; ++kc) {
      #pragma unroll
      for (int nt = 0; nt < 16; ++nt) {
        bf16x8 wf = *(const bf16x8*)(W + (size_t)(nt * 16 + li) * NCH + kc * 32 + qd * 8);
        acc[nt] = __builtin_amdgcn_mfma_f32_16x16x32_bf16(hf[kc], wf, acc[nt], 0, 0, 0);
      }
    }
    bf16* out = (pass ? kT : qT) + ((size_t)b * NSP + i0 + w * 16) * NCH;
    #pragma unroll
    for (int nt = 0; nt < 16; ++nt) {
      float bb = bias[nt * 16 + li] * bsc;
      #pragma unroll
      for (int r = 0; r < 4; ++r)
        out[(size_t)(qd * 4 + r) * NCH + nt * 16 + li] = (bf16)(acc[nt][r] + bb);
    }
  }

  {  // v pass: wave handles co in [w*64, w*64+64)
    const bf16* W = wbf + 2ull * 65536;
    f32x4 acc[16];
    #pragma unroll
    for (int t = 0; t < 16; ++t) acc[t] = (f32x4){0.f, 0.f, 0.f, 0.f};
    for (int kc = 0; kc < 8; ++kc) {
      bf16x8 hb[4];
      #pragma unroll
      for (int nt = 0; nt < 4; ++nt)
        hb[nt] = *(const bf16x8*)(hnT + ((size_t)b * NSP + i0 + nt * 16 + li) * NCH + kc * 32 + qd * 8);
      #pragma unroll
      for (int mt = 0; mt < 4; ++mt) {
        bf16x8 wf = *(const bf16x8*)(W + (size_t)(w * 64 + mt * 16 + li) * NCH + kc * 32 + qd * 8);
        #pragma unroll
        for (int nt = 0; nt < 4; ++nt)
          acc[mt * 4 + nt] = __builtin_amdgcn_mfma_f32_16x16x32_bf16(wf, hb[nt], acc[mt * 4 + nt], 0, 0, 0);
      }
    }
    #pragma unroll
    for (int mt = 0; mt < 4; ++mt) {
      #pragma unroll
      for (int r = 0; r < 4; ++r) {
        int co = w * 64 + mt * 16 + qd * 4 + r;
        float bb = bv[co];
        #pragma unroll
        for (int nt = 0; nt < 4; ++nt)
          vM[((size_t)b * NCH + co) * NSP + i0 + nt * 16 + li] = (bf16)(acc[mt * 4 + nt][r] + bb);
      }
    }
  }
}

// ---------------- k4: flash attention --------------------------------------
// 512 blocks (b, i-tile 64), 4 waves, each wave owns 16 query rows.
// j loop in chunks of 32; K/V tiles staged in LDS shared by the 4 waves.
__global__ __launch_bounds__(256) void k_attn(const bf16* __restrict__ qT,
    const bf16* __restrict__ kT, const bf16* __restrict__ vM,
    bf16* __restrict__ aoT) {
  __shared__ bf16 Kt[32][264];     // [j][c], pad 8 halves -> 2-way (free)
  __shared__ bf16 Vt[256][40];     // [c][j], pad 8 halves
  __shared__ bf16 Pt[4][16][40];   // per-wave P [i][j] for B-frag reads

  const int b  = blockIdx.x >> 6;
  const int i0 = (blockIdx.x & 63) * 64;
  const int tid = threadIdx.x, w = tid >> 6, lane = tid & 63;
  const int li = lane & 15, qd = lane >> 4;

  const bf16* kT_b = kT + (size_t)b * NSP * NCH;
  const bf16* v_b  = vM + (size_t)b * NCH * NSP;

  bf16x8 qf[8];
  {
    const bf16* qp = qT + ((size_t)b * NSP + i0 + w * 16 + li) * NCH + qd * 8;
    #pragma unroll
    for (int kc = 0; kc < 8; ++kc) qf[kc] = *(const bf16x8*)(qp + kc * 32);
  }

  f32x4 Oa[16];
  #pragma unroll
  for (int t = 0; t < 16; ++t) Oa[t] = (f32x4){0.f, 0.f, 0.f, 0.f};
  float mrow[4] = {-1e30f, -1e30f, -1e30f, -1e30f};
  float lrow[4] = {0.f, 0.f, 0.f, 0.f};

  for (int jc = 0; jc < 128; ++jc) {
    __syncthreads();
    #pragma unroll
    for (int p = 0; p < 4; ++p) {            // stage K: 32 x 256 halves
      int idx = p * 256 + tid;
      int row = idx >> 5, ch = idx & 31;
      *(int4*)(&Kt[row][ch * 8]) =
          *(const int4*)(kT_b + (size_t)(jc * 32 + row) * NCH + ch * 8);
    }
    #pragma unroll
    for (int p = 0; p < 4; ++p) {            // stage V: 256 x 32 halves
      int idx = p * 256 + tid;
      int row = idx >> 2, ch = idx & 3;
      *(int4*)(&Vt[row][ch * 8]) =
          *(const int4*)(v_b + (size_t)row * NSP + jc * 32 + ch * 8);
    }
    __syncthreads();

    // S = Q^T K for 16 i x 32 j (two 16x16 D-tiles)
    f32x4 S0 = {0.f, 0.f, 0.f, 0.f}, S1 = {0.f, 0.f, 0.f, 0.f};
    #pragma unroll
    for (int kc = 0; kc < 8; ++kc) {
      bf16x8 kf = *(const bf16x8*)(&Kt[li][kc * 32 + qd * 8]);
      S0 = __builtin_amdgcn_mfma_f32_16x16x32_bf16(qf[kc], kf, S0, 0, 0, 0);
    }
    #pragma unroll
    for (int kc = 0; kc < 8; ++kc) {
      bf16x8 kf = *(const bf16x8*)(&Kt[16 + li][kc * 32 + qd * 8]);
      S1 = __builtin_amdgcn_mfma_f32_16x16x32_bf16(qf[kc], kf, S1, 0, 0, 0);
    }

    // online softmax update; write P (bf16) in [i][j] layout
    float alpha[4];
    #pragma unroll
    for (int r = 0; r < 4; ++r) {
      float mx = red16_max(fmaxf(S0[r], S1[r]));
      float mn = fmaxf(mrow[r], mx);
      alpha[r] = __expf(mrow[r] - mn);
      mrow[r] = mn;
      float p0 = __expf(S0[r] - mn);
      float p1 = __expf(S1[r] - mn);
      lrow[r] = lrow[r] * alpha[r] + red16_sum(p0 + p1);
      Pt[w][qd * 4 + r][li]      = (bf16)p0;
      Pt[w][qd * 4 + r][16 + li] = (bf16)p1;
    }
    {
      float av = row2col(alpha, li);         // alpha indexed by O-column i
      #pragma unroll
      for (int t = 0; t < 16; ++t) {
        Oa[t][0] *= av; Oa[t][1] *= av; Oa[t][2] *= av; Oa[t][3] *= av;
      }
    }
    __syncthreads();                         // P write -> P read ordering

    // O += V P^T : one K=32 MFMA per 16-channel tile
    bf16x8 pf = *(const bf16x8*)(&Pt[w][li][qd * 8]);
    #pragma unroll
    for (int ct = 0; ct < 16; ++ct) {
      bf16x8 vf = *(const bf16x8*)(&Vt[ct * 16 + li][qd * 8]);
      Oa[ct] = __builtin_amdgcn_mfma_f32_16x16x32_bf16(vf, pf, Oa[ct], 0, 0, 0);
    }
  }

  // epilogue: O /= l, store aoT[b][i][c] (bf16), 8B packed stores
  float linv[4];
  #pragma unroll
  for (int r = 0; r < 4; ++r) linv[r] = 1.f / lrow[r];
  float lv = row2col(linv, li);

  bf16* op = aoT + ((size_t)b * NSP + i0 + w * 16 + li) * NCH;
  #pragma unroll
  for (int ct = 0; ct < 16; ++ct) {
    union { bf16 h[4]; uint2 u; } pk;
    pk.h[0] = (bf16)(Oa[ct][0] * lv);
    pk.h[1] = (bf16)(Oa[ct][1] * lv);
    pk.h[2] = (bf16)(Oa[ct][2] * lv);
    pk.h[3] = (bf16)(Oa[ct][3] * lv);
    *(uint2*)(op + ct * 16 + qd * 4) = pk.u;
  }
}

// ---------------- k5: out = x + wo @ ao + bo -------------------------------
__global__ __launch_bounds__(256) void k_out(const bf16* __restrict__ aoT,
    const bf16* __restrict__ wo, const float* __restrict__ bo,
    const float* __restrict__ x, float* __restrict__ out) {
  const int b  = blockIdx.x >> 6;
  const int i0 = (blockIdx.x & 63) * 64;
  const int tid = threadIdx.x, w = tid >> 6, lane = tid & 63;
  const int li = lane & 15, qd = lane >> 4;

  f32x4 acc[16];
  #pragma unroll
  for (int t = 0; t < 16; ++t) acc[t] = (f32x4){0.f, 0.f, 0.f, 0.f};
  for (int kc = 0; kc < 8; ++kc) {
    bf16x8 ab[4];
    #pragma unroll
    for (int nt = 0; nt < 4; ++nt)
      ab[nt] = *(const bf16x8*)(aoT + ((size_t)b * NSP + i0 + nt * 16 + li) * NCH + kc * 32 + qd * 8);
    #pragma unroll
    for (int mt = 0; mt < 4; ++mt) {
      bf16x8 wf = *(const bf16x8*)(wo + (size_t)(w * 64 + mt * 16 + li) * NCH + kc * 32 + qd * 8);
      #pragma unroll
      for (int nt = 0; nt < 4; ++nt)
        acc[mt * 4 + nt] = __builtin_amdgcn_mfma_f32_16x16x32_bf16(wf, ab[nt], acc[mt * 4 + nt], 0, 0, 0);
    }
  }
  #pragma unroll
  for (int mt = 0; mt < 4; ++mt) {
    #pragma unroll
    for (int r = 0; r < 4; ++r) {
      int co = w * 64 + mt * 16 + qd * 4 + r;
      float bb = bo[co];
      #pragma unroll
      for (int nt = 0; nt < 4; ++nt) {
        size_t idx = ((size_t)b * NCH + co) * NSP + i0 + nt * 16 + li;
        out[idx] = acc[mt * 4 + nt][r] + bb + x[idx];
      }
    }
  }
}

// ---------------- host ------------------------------------------------------
extern "C" void kernel_launch(void* const* d_in, const int* in_sizes, int n_in,
                              void* d_out, int out_size, void* d_ws, size_t ws_size,
                              hipStream_t stream) {
  (void)in_sizes; (void)n_in; (void)out_size; (void)ws_size;
  const float* x   = (const float*)d_in[0];
  const float* gsc = (const float*)d_in[1];
  const float* gbi = (const float*)d_in[2];
  const float* wq  = (const float*)d_in[3];
  const float* bq  = (const float*)d_in[4];
  const float* wk  = (const float*)d_in[5];
  const float* bk  = (const float*)d_in[6];
  const float* wv  = (const float*)d_in[7];
  const float* bv  = (const float*)d_in[8];
  const float* wo  = (const float*)d_in[9];
  const float* bo  = (const float*)d_in[10];

  char* ws = (char*)d_ws;
  const size_t MB16 = 16777216u;
  bf16*  wbf   = (bf16*)(ws);                         // 512 KB (4x 256x256 bf16)
  float* stats = (float*)(ws + 524288);               // 512 B
  bf16*  hnT   = (bf16*)(ws + (1u << 20));            // 16 MB [b][n][c]
  bf16*  qT    = (bf16*)(ws + (1u << 20) + 1 * MB16); // 16 MB [b][n][c]
  bf16*  kTp   = (bf16*)(ws + (1u << 20) + 2 * MB16); // 16 MB [b][n][c]
  bf16*  vM    = (bf16*)(ws + (1u << 20) + 3 * MB16); // 16 MB [b][c][n]
  bf16*  aoT   = (bf16*)(ws + (1u << 20) + 4 * MB16); // 16 MB [b][n][c]
  float* out   = (float*)d_out;

  k_wconv  <<<1024, 256, 0, stream>>>(wq, wk, wv, wo, wbf);
  k_gnstats<<<  64, 256, 0, stream>>>(x, stats);
  k_gnapply<<<2048, 256, 0, stream>>>(x, stats, gsc, gbi, hnT);
  k_qkv    <<< 512, 256, 0, stream>>>(hnT, wbf, bq, bk, bv, qT, kTp, vM);
  k_attn   <<< 512, 256, 0, stream>>>(qT, kTp, vM, aoT);
  k_out    <<< 512, 256, 0, stream>>>(aoT, wbf + 3ull * 65536, bo, x, out);
}

// Round 2
// 578.549 us; speedup vs baseline: 1.2374x; 1.2374x over previous
//
#include <hip/hip_runtime.h>

typedef __bf16 bf16;
typedef __bf16 bf16x8 __attribute__((ext_vector_type(8)));
typedef float  f32x4  __attribute__((ext_vector_type(4)));

#define NSP 4096   // h*w
#define NCH 256    // channels
#define NB  8      // batch

static __device__ __forceinline__ float red16_sum(float v) {
  v += __shfl_xor(v, 1);
  v += __shfl_xor(v, 2);
  v += __shfl_xor(v, 4);
  v += __shfl_xor(v, 8);
  return v;
}
// broadcast row-indexed values (rows qd*4+r, uniform across 16 lanes of a quad)
// to column-indexed lanes (index = lane&15)
static __device__ __forceinline__ float row2col(const float a[4], int li) {
  int src = (li >> 2) << 4;
  float t0 = __shfl(a[0], src);
  float t1 = __shfl(a[1], src);
  float t2 = __shfl(a[2], src);
  float t3 = __shfl(a[3], src);
  int r = li & 3;
  return (r == 0) ? t0 : (r == 1) ? t1 : (r == 2) ? t2 : t3;
}

// ---------------- k0: weights fp32 -> bf16 (wq gets 1/sqrt(c)=1/16) -------
__global__ __launch_bounds__(256) void k_wconv(
    const float* __restrict__ wq, const float* __restrict__ wk,
    const float* __restrict__ wv, const float* __restrict__ wo,
    bf16* __restrict__ wbf) {
  int g = blockIdx.x * 256 + threadIdx.x;
  int m = g >> 16, idx = g & 65535;
  const float* src = (m == 0) ? wq : (m == 1) ? wk : (m == 2) ? wv : wo;
  float sc = (m == 0) ? 0.0625f : 1.0f;
  wbf[g] = (bf16)(src[idx] * sc);
}

// ---------------- k1a: partial GN sums, 8 blocks per (b,g) ----------------
__global__ __launch_bounds__(256) void k_gnstats1(const float* __restrict__ x,
                                                  float2* __restrict__ part) {
  int blk = blockIdx.x;                         // 512 = 64 bg * 8 seg
  int bg = blk >> 3, seg = blk & 7;
  const float4* p = (const float4*)(x + (size_t)bg * 131072 + seg * 16384);
  float s = 0.f, s2 = 0.f;
  for (int i = threadIdx.x; i < 4096; i += 256) {
    float4 v = p[i];
    s  += v.x + v.y + v.z + v.w;
    s2 += v.x*v.x + v.y*v.y + v.z*v.z + v.w*v.w;
  }
  for (int off = 1; off < 64; off <<= 1) {
    s  += __shfl_xor(s, off);
    s2 += __shfl_xor(s2, off);
  }
  __shared__ float a1[4], a2[4];
  int w = threadIdx.x >> 6, lane = threadIdx.x & 63;
  if (lane == 0) { a1[w] = s; a2[w] = s2; }
  __syncthreads();
  if (threadIdx.x == 0)
    part[blk] = make_float2(a1[0]+a1[1]+a1[2]+a1[3], a2[0]+a2[1]+a2[2]+a2[3]);
}

// ---------------- k1b: finalize stats --------------------------------------
__global__ __launch_bounds__(64) void k_gnstats2(const float2* __restrict__ part,
                                                 float* __restrict__ stats) {
  int bg = threadIdx.x;                         // 64
  float s = 0.f, s2 = 0.f;
  #pragma unroll
  for (int k = 0; k < 8; ++k) {
    float2 v = part[bg * 8 + k];
    s += v.x; s2 += v.y;
  }
  float mean = s * (1.f / 131072.f);
  float var  = s2 * (1.f / 131072.f) - mean * mean;
  stats[bg * 2]     = mean;
  stats[bg * 2 + 1] = rsqrtf(var + 1e-6f);
}

// ---------------- k2: GN apply + transpose -> hnT[b][n][c] bf16 -----------
__global__ __launch_bounds__(256) void k_gnapply(const float* __restrict__ x,
    const float* __restrict__ stats, const float* __restrict__ gsc,
    const float* __restrict__ gbi, bf16* __restrict__ hnT) {
  __shared__ float T[64][65];
  int blk = blockIdx.x;                         // 2048
  int b = blk >> 8, ct = (blk >> 6) & 3, it = blk & 63;
  int tid = threadIdx.x;
  #pragma unroll 4
  for (int p = 0; p < 16; ++p) {
    int cc = p * 4 + (tid >> 6), ii = tid & 63;
    int c = ct * 64 + cc;
    float mean = stats[(b * 8 + (c >> 5)) * 2];
    float rstd = stats[(b * 8 + (c >> 5)) * 2 + 1];
    float v = x[((size_t)b * NCH + c) * NSP + it * 64 + ii];
    T[cc][ii] = (v - mean) * rstd * gsc[c] + gbi[c];
  }
  __syncthreads();
  #pragma unroll 4
  for (int p = 0; p < 16; ++p) {
    int ii = p * 4 + (tid >> 6), cc = tid & 63;
    hnT[((size_t)b * NSP + it * 64 + ii) * NCH + ct * 64 + cc] = (bf16)T[cc][ii];
  }
}

// ---------------- k3: QKV projection, one pass per block -------------------
// All passes: D[m=co][n=i] = mfma(A=W rows, B=hnT rows).
// q/k store transposed to qT/kT[b][i][c] (8B packed along co via reg index);
// v stores vM[b][c][n].
__global__ __launch_bounds__(256, 4) void k_qkv(const bf16* __restrict__ hnT,
    const bf16* __restrict__ wbf, const float* __restrict__ bq,
    const float* __restrict__ bk, const float* __restrict__ bv,
    bf16* __restrict__ qT, bf16* __restrict__ kT, bf16* __restrict__ vM) {
  const int pass = blockIdx.x >> 9;             // 0:q 1:k 2:v
  const int rem  = blockIdx.x & 511;
  const int b  = rem >> 6;
  const int i0 = (rem & 63) * 64;
  const int tid = threadIdx.x, w = tid >> 6, lane = tid & 63;
  const int li = lane & 15, qd = lane >> 4;

  const bf16* W = wbf + (size_t)pass * 65536;
  f32x4 acc[16];
  #pragma unroll
  for (int t = 0; t < 16; ++t) acc[t] = (f32x4){0.f, 0.f, 0.f, 0.f};

  for (int kc = 0; kc < 8; ++kc) {
    bf16x8 hb[4];
    #pragma unroll
    for (int nt = 0; nt < 4; ++nt)
      hb[nt] = *(const bf16x8*)(hnT + ((size_t)b * NSP + i0 + nt * 16 + li) * NCH + kc * 32 + qd * 8);
    #pragma unroll
    for (int mt = 0; mt < 4; ++mt) {
      bf16x8 wf = *(const bf16x8*)(W + (size_t)(w * 64 + mt * 16 + li) * NCH + kc * 32 + qd * 8);
      #pragma unroll
      for (int nt = 0; nt < 4; ++nt)
        acc[mt * 4 + nt] = __builtin_amdgcn_mfma_f32_16x16x32_bf16(wf, hb[nt], acc[mt * 4 + nt], 0, 0, 0);
    }
  }

  if (pass < 2) {
    const float* bias = pass ? bk : bq;
    const float bsc = pass ? 1.0f : 0.0625f;
    bf16* out = (pass ? kT : qT) + ((size_t)b * NSP + i0) * NCH;
    #pragma unroll
    for (int mt = 0; mt < 4; ++mt) {
      float bb[4];
      #pragma unroll
      for (int r = 0; r < 4; ++r) bb[r] = bias[w * 64 + mt * 16 + qd * 4 + r] * bsc;
      #pragma unroll
      for (int nt = 0; nt < 4; ++nt) {
        union { bf16 h[4]; uint2 u; } pk;
        #pragma unroll
        for (int r = 0; r < 4; ++r) pk.h[r] = (bf16)(acc[mt * 4 + nt][r] + bb[r]);
        *(uint2*)(out + (size_t)(nt * 16 + li) * NCH + w * 64 + mt * 16 + qd * 4) = pk.u;
      }
    }
  } else {
    #pragma unroll
    for (int mt = 0; mt < 4; ++mt) {
      #pragma unroll
      for (int r = 0; r < 4; ++r) {
        int co = w * 64 + mt * 16 + qd * 4 + r;
        float bb = bv[co];
        #pragma unroll
        for (int nt = 0; nt < 4; ++nt)
          vM[((size_t)b * NCH + co) * NSP + i0 + nt * 16 + li] = (bf16)(acc[mt * 4 + nt][r] + bb);
      }
    }
  }
}

// ---------------- k4: flash attention, no-max softmax, j-split x2 ----------
// grid 1024 = 8b * 64 itile * 2 jsplit; 4 waves x 16 query rows.
// LDS 37.9KB -> 4 blocks/CU. Kt/Vt XOR-swizzled (16B block granularity).
__global__ __launch_bounds__(256, 4) void k_attn(const bf16* __restrict__ qT,
    const bf16* __restrict__ kT, const bf16* __restrict__ vM,
    bf16* __restrict__ Op0, bf16* __restrict__ Op1, float* __restrict__ Lp) {
  __shared__ bf16 Kt[32 * 256];   // [j][c16blk swizzled: pb = cb ^ (j&7)]
  __shared__ bf16 Vt[256 * 32];   // [c][j16blk swizzled: pb = jb ^ (c&3)]
  __shared__ bf16 Pt[4][16][40];  // per-wave P [i][j], stride 40 spreads banks

  const int b  = blockIdx.x >> 7;
  const int it = (blockIdx.x >> 1) & 63;
  const int js = blockIdx.x & 1;
  const int i0 = it * 64;
  const int tid = threadIdx.x, w = tid >> 6, lane = tid & 63;
  const int li = lane & 15, qd = lane >> 4;

  const bf16* kT_b = kT + (size_t)b * NSP * NCH;
  const bf16* v_b  = vM + (size_t)b * NCH * NSP;

  bf16x8 qf[8];
  {
    const bf16* qp = qT + ((size_t)b * NSP + i0 + w * 16 + li) * NCH + qd * 8;
    #pragma unroll
    for (int kc = 0; kc < 8; ++kc) qf[kc] = *(const bf16x8*)(qp + kc * 32);
  }

  f32x4 Oa[16];
  #pragma unroll
  for (int t = 0; t < 16; ++t) Oa[t] = (f32x4){0.f, 0.f, 0.f, 0.f};
  float lacc[4] = {0.f, 0.f, 0.f, 0.f};

  for (int jc = 0; jc < 64; ++jc) {
    const int j0 = js * 2048 + jc * 32;
    __syncthreads();                           // prev iter's reads done
    #pragma unroll
    for (int p = 0; p < 4; ++p) {              // stage K: 32 rows x 256c
      int idx = p * 256 + tid;
      int row = idx >> 5, cb = idx & 31;
      int pb = cb ^ (row & 7);
      *(int4*)(&Kt[row * 256 + pb * 8]) =
          *(const int4*)(kT_b + (size_t)(j0 + row) * NCH + cb * 8);
    }
    #pragma unroll
    for (int p = 0; p < 4; ++p) {              // stage V: 256 rows x 32j
      int idx = p * 256 + tid;
      int row = idx >> 2, jb = idx & 3;
      int pb = jb ^ (row & 3);
      *(int4*)(&Vt[row * 32 + pb * 8]) =
          *(const int4*)(v_b + (size_t)row * NSP + j0 + jb * 8);
    }
    __syncthreads();

    f32x4 S0 = {0.f, 0.f, 0.f, 0.f}, S1 = {0.f, 0.f, 0.f, 0.f};
    #pragma unroll
    for (int kc = 0; kc < 8; ++kc) {
      int pb = (kc * 4 + qd) ^ (li & 7);
      bf16x8 kf = *(const bf16x8*)(&Kt[li * 256 + pb * 8]);
      S0 = __builtin_amdgcn_mfma_f32_16x16x32_bf16(qf[kc], kf, S0, 0, 0, 0);
    }
    #pragma unroll
    for (int kc = 0; kc < 8; ++kc) {
      int pb = (kc * 4 + qd) ^ (li & 7);
      bf16x8 kf = *(const bf16x8*)(&Kt[(16 + li) * 256 + pb * 8]);
      S1 = __builtin_amdgcn_mfma_f32_16x16x32_bf16(qf[kc], kf, S1, 0, 0, 0);
    }

    // softmax numerator (shift-invariant; fixed -8 shift for range safety)
    #pragma unroll
    for (int r = 0; r < 4; ++r) {
      float e0 = __expf(S0[r] - 8.f);
      float e1 = __expf(S1[r] - 8.f);
      lacc[r] += e0 + e1;
      Pt[w][qd * 4 + r][li]      = (bf16)e0;
      Pt[w][qd * 4 + r][16 + li] = (bf16)e1;
    }
    // Pt is wave-private: compiler's lgkmcnt ordering suffices, no barrier.

    bf16x8 pf = *(const bf16x8*)(&Pt[w][li][qd * 8]);
    #pragma unroll
    for (int ct = 0; ct < 16; ++ct) {
      int pb = qd ^ (li & 3);
      bf16x8 vf = *(const bf16x8*)(&Vt[(ct * 16 + li) * 32 + pb * 8]);
      Oa[ct] = __builtin_amdgcn_mfma_f32_16x16x32_bf16(vf, pf, Oa[ct], 0, 0, 0);
    }
  }

  float lr[4], linv[4];
  #pragma unroll
  for (int r = 0; r < 4; ++r) lr[r] = red16_sum(lacc[r]);
  #pragma unroll
  for (int r = 0; r < 4; ++r) linv[r] = 1.f / lr[r];
  float lv = row2col(linv, li);

  bf16* Op = js ? Op1 : Op0;
  bf16* op = Op + ((size_t)b * NSP + i0 + w * 16 + li) * NCH;
  #pragma unroll
  for (int ct = 0; ct < 16; ++ct) {
    union { bf16 h[4]; uint2 u; } pk;
    pk.h[0] = (bf16)(Oa[ct][0] * lv);
    pk.h[1] = (bf16)(Oa[ct][1] * lv);
    pk.h[2] = (bf16)(Oa[ct][2] * lv);
    pk.h[3] = (bf16)(Oa[ct][3] * lv);
    *(uint2*)(op + ct * 16 + qd * 4) = pk.u;
  }
  if (li == 0) {
    float* lp = Lp + js * 32768 + b * 4096 + i0 + w * 16;
    #pragma unroll
    for (int r = 0; r < 4; ++r) lp[qd * 4 + r] = lr[r];
  }
}

// ---------------- k4b: combine the two j-split partials --------------------
// aoT may alias Op0 (each element read+written by exactly one thread).
__global__ __launch_bounds__(256) void k_combine(const bf16* __restrict__ Op0,
    const bf16* __restrict__ Op1, const float* __restrict__ Lp,
    bf16* __restrict__ aoT) {
  int g = blockIdx.x * 256 + threadIdx.x;      // 0..1048575
  int bi = g >> 5, cb = g & 31;
  float l0 = Lp[bi], l1 = Lp[32768 + bi];
  float inv = 1.f / (l0 + l1);
  float w0 = l0 * inv, w1 = l1 * inv;
  bf16x8 a = *(const bf16x8*)(Op0 + (size_t)bi * NCH + cb * 8);
  bf16x8 c = *(const bf16x8*)(Op1 + (size_t)bi * NCH + cb * 8);
  bf16x8 o;
  #pragma unroll
  for (int k = 0; k < 8; ++k) o[k] = (bf16)(w0 * (float)a[k] + w1 * (float)c[k]);
  *(bf16x8*)(aoT + (size_t)bi * NCH + cb * 8) = o;
}

// ---------------- k5: out = x + wo @ ao + bo, co-split x2 ------------------
__global__ __launch_bounds__(256, 4) void k_out(const bf16* __restrict__ aoT,
    const bf16* __restrict__ wo, const float* __restrict__ bo,
    const float* __restrict__ x, float* __restrict__ out) {
  const int b  = blockIdx.x >> 7;
  const int i0 = ((blockIdx.x >> 1) & 63) * 64;
  const int ch = blockIdx.x & 1;
  const int tid = threadIdx.x, w = tid >> 6, lane = tid & 63;
  const int li = lane & 15, qd = lane >> 4;
  const int cb0 = ch * 128 + w * 32;

  f32x4 acc[8];
  #pragma unroll
  for (int t = 0; t < 8; ++t) acc[t] = (f32x4){0.f, 0.f, 0.f, 0.f};
  for (int kc = 0; kc < 8; ++kc) {
    bf16x8 ab[4];
    #pragma unroll
    for (int nt = 0; nt < 4; ++nt)
      ab[nt] = *(const bf16x8*)(aoT + ((size_t)b * NSP + i0 + nt * 16 + li) * NCH + kc * 32 + qd * 8);
    #pragma unroll
    for (int mt = 0; mt < 2; ++mt) {
      bf16x8 wf = *(const bf16x8*)(wo + (size_t)(cb0 + mt * 16 + li) * NCH + kc * 32 + qd * 8);
      #pragma unroll
      for (int nt = 0; nt < 4; ++nt)
        acc[mt * 4 + nt] = __builtin_amdgcn_mfma_f32_16x16x32_bf16(wf, ab[nt], acc[mt * 4 + nt], 0, 0, 0);
    }
  }
  #pragma unroll
  for (int mt = 0; mt < 2; ++mt) {
    #pragma unroll
    for (int r = 0; r < 4; ++r) {
      int co = cb0 + mt * 16 + qd * 4 + r;
      float bb = bo[co];
      #pragma unroll
      for (int nt = 0; nt < 4; ++nt) {
        size_t idx = ((size_t)b * NCH + co) * NSP + i0 + nt * 16 + li;
        out[idx] = acc[mt * 4 + nt][r] + bb + x[idx];
      }
    }
  }
}

// ---------------- host ------------------------------------------------------
extern "C" void kernel_launch(void* const* d_in, const int* in_sizes, int n_in,
                              void* d_out, int out_size, void* d_ws, size_t ws_size,
                              hipStream_t stream) {
  (void)in_sizes; (void)n_in; (void)out_size; (void)ws_size;
  const float* x   = (const float*)d_in[0];
  const float* gsc = (const float*)d_in[1];
  const float* gbi = (const float*)d_in[2];
  const float* wq  = (const float*)d_in[3];
  const float* bq  = (const float*)d_in[4];
  const float* wk  = (const float*)d_in[5];
  const float* bk  = (const float*)d_in[6];
  const float* wv  = (const float*)d_in[7];
  const float* bv  = (const float*)d_in[8];
  const float* wo  = (const float*)d_in[9];
  const float* bo  = (const float*)d_in[10];

  char* ws = (char*)d_ws;
  const size_t MB16 = 16777216u;
  bf16*   wbf   = (bf16*)(ws);                         // 512 KB
  float*  stats = (float*)(ws + 524288);               // 512 B
  float2* part  = (float2*)(ws + 528384);              // 4 KB
  float*  Lp    = (float*)(ws + 655360);               // 256 KB
  bf16*   hnT   = (bf16*)(ws + (1u << 20));            // 16 MB; reused: Op0 -> aoT
  bf16*   qT    = (bf16*)(ws + (1u << 20) + 1 * MB16);
  bf16*   kTp   = (bf16*)(ws + (1u << 20) + 2 * MB16);
  bf16*   vM    = (bf16*)(ws + (1u << 20) + 3 * MB16);
  bf16*   Op1   = (bf16*)(ws + (1u << 20) + 4 * MB16);
  bf16*   Op0   = hnT;   // hnT dead after k_qkv
  bf16*   aoT   = Op0;   // combine rewrites in place
  float*  out   = (float*)d_out;

  k_wconv   <<<1024, 256, 0, stream>>>(wq, wk, wv, wo, wbf);
  k_gnstats1<<< 512, 256, 0, stream>>>(x, part);
  k_gnstats2<<<   1,  64, 0, stream>>>(part, stats);
  k_gnapply <<<2048, 256, 0, stream>>>(x, stats, gsc, gbi, hnT);
  k_qkv     <<<1536, 256, 0, stream>>>(hnT, wbf, bq, bk, bv, qT, kTp, vM);
  k_attn    <<<1024, 256, 0, stream>>>(qT, kTp, vM, Op0, Op1, Lp);
  k_combine <<<4096, 256, 0, stream>>>(Op0, Op1, Lp, aoT);
  k_out     <<<1024, 256, 0, stream>>>(aoT, wbf + 3ull * 65536, bo, x, out);
}

// Round 3
// 473.001 us; speedup vs baseline: 1.5135x; 1.2231x over previous
//
#include <hip/hip_runtime.h>

typedef __bf16 bf16;
typedef __bf16 bf16x8 __attribute__((ext_vector_type(8)));
typedef float  f32x4  __attribute__((ext_vector_type(4)));

#define NSP 4096   // h*w
#define NCH 256    // channels
#define NB  8      // batch

static __device__ __forceinline__ float red16_sum(float v) {
  v += __shfl_xor(v, 1);
  v += __shfl_xor(v, 2);
  v += __shfl_xor(v, 4);
  v += __shfl_xor(v, 8);
  return v;
}
// broadcast row-indexed values (rows qd*4+r, uniform across 16 lanes of a quad)
// to column-indexed lanes (index = lane&15)
static __device__ __forceinline__ float row2col(const float a[4], int li) {
  int src = (li >> 2) << 4;
  float t0 = __shfl(a[0], src);
  float t1 = __shfl(a[1], src);
  float t2 = __shfl(a[2], src);
  float t3 = __shfl(a[3], src);
  int r = li & 3;
  return (r == 0) ? t0 : (r == 1) ? t1 : (r == 2) ? t2 : t3;
}

// global(16B per lane) -> LDS at wave-uniform base + lane*16
static __device__ __forceinline__ void glds16(const bf16* g, bf16* l) {
  __builtin_amdgcn_global_load_lds(
      (const __attribute__((address_space(1))) unsigned int*)g,
      (__attribute__((address_space(3))) unsigned int*)l, 16, 0, 0);
}

// ---------------- k0: weights fp32 -> bf16 (wq gets 1/sqrt(c)=1/16) -------
__global__ __launch_bounds__(256) void k_wconv(
    const float* __restrict__ wq, const float* __restrict__ wk,
    const float* __restrict__ wv, const float* __restrict__ wo,
    bf16* __restrict__ wbf) {
  int g = blockIdx.x * 256 + threadIdx.x;
  int m = g >> 16, idx = g & 65535;
  const float* src = (m == 0) ? wq : (m == 1) ? wk : (m == 2) ? wv : wo;
  float sc = (m == 0) ? 0.0625f : 1.0f;
  wbf[g] = (bf16)(src[idx] * sc);
}

// ---------------- k1a: partial GN sums, 8 blocks per (b,g) ----------------
__global__ __launch_bounds__(256) void k_gnstats1(const float* __restrict__ x,
                                                  float2* __restrict__ part) {
  int blk = blockIdx.x;                         // 512 = 64 bg * 8 seg
  int bg = blk >> 3, seg = blk & 7;
  const float4* p = (const float4*)(x + (size_t)bg * 131072 + seg * 16384);
  float s = 0.f, s2 = 0.f;
  for (int i = threadIdx.x; i < 4096; i += 256) {
    float4 v = p[i];
    s  += v.x + v.y + v.z + v.w;
    s2 += v.x*v.x + v.y*v.y + v.z*v.z + v.w*v.w;
  }
  for (int off = 1; off < 64; off <<= 1) {
    s  += __shfl_xor(s, off);
    s2 += __shfl_xor(s2, off);
  }
  __shared__ float a1[4], a2[4];
  int w = threadIdx.x >> 6, lane = threadIdx.x & 63;
  if (lane == 0) { a1[w] = s; a2[w] = s2; }
  __syncthreads();
  if (threadIdx.x == 0)
    part[blk] = make_float2(a1[0]+a1[1]+a1[2]+a1[3], a2[0]+a2[1]+a2[2]+a2[3]);
}

// ---------------- k1b: finalize stats --------------------------------------
__global__ __launch_bounds__(64) void k_gnstats2(const float2* __restrict__ part,
                                                 float* __restrict__ stats) {
  int bg = threadIdx.x;                         // 64
  float s = 0.f, s2 = 0.f;
  #pragma unroll
  for (int k = 0; k < 8; ++k) {
    float2 v = part[bg * 8 + k];
    s += v.x; s2 += v.y;
  }
  float mean = s * (1.f / 131072.f);
  float var  = s2 * (1.f / 131072.f) - mean * mean;
  stats[bg * 2]     = mean;
  stats[bg * 2 + 1] = rsqrtf(var + 1e-6f);
}

// ---------------- k2: GN apply + transpose -> hnT[b][n][c] bf16 -----------
__global__ __launch_bounds__(256) void k_gnapply(const float* __restrict__ x,
    const float* __restrict__ stats, const float* __restrict__ gsc,
    const float* __restrict__ gbi, bf16* __restrict__ hnT) {
  __shared__ float T[64][65];
  int blk = blockIdx.x;                         // 2048
  int b = blk >> 8, ct = (blk >> 6) & 3, it = blk & 63;
  int tid = threadIdx.x;
  #pragma unroll 4
  for (int p = 0; p < 16; ++p) {
    int cc = p * 4 + (tid >> 6), ii = tid & 63;
    int c = ct * 64 + cc;
    float mean = stats[(b * 8 + (c >> 5)) * 2];
    float rstd = stats[(b * 8 + (c >> 5)) * 2 + 1];
    float v = x[((size_t)b * NCH + c) * NSP + it * 64 + ii];
    T[cc][ii] = (v - mean) * rstd * gsc[c] + gbi[c];
  }
  __syncthreads();
  #pragma unroll 4
  for (int p = 0; p < 16; ++p) {
    int ii = p * 4 + (tid >> 6), cc = tid & 63;
    hnT[((size_t)b * NSP + it * 64 + ii) * NCH + ct * 64 + cc] = (bf16)T[cc][ii];
  }
}

// ---------------- k3: QKV projection, one pass per block -------------------
// q: qT[b][i][c].  k: kS pre-swizzled K tiles (32 j x 256 c, granule
// pb = cb ^ (j&7)).  v: vS pre-swizzled V tiles (256 c x 32 j, granule
// pb = jb ^ ((c>>1)&3)).  Tiles are the exact linear image of k_attn's LDS.
__global__ __launch_bounds__(256, 4) void k_qkv(const bf16* __restrict__ hnT,
    const bf16* __restrict__ wbf, const float* __restrict__ bq,
    const float* __restrict__ bk, const float* __restrict__ bv,
    bf16* __restrict__ qT, bf16* __restrict__ kS, bf16* __restrict__ vS) {
  const int pass = blockIdx.x >> 9;             // 0:q 1:k 2:v
  const int rem  = blockIdx.x & 511;
  const int b  = rem >> 6;
  const int i0 = (rem & 63) * 64;
  const int tid = threadIdx.x, w = tid >> 6, lane = tid & 63;
  const int li = lane & 15, qd = lane >> 4;
  const bf16* W = wbf + (size_t)pass * 65536;

  if (pass == 2) {  // v: D[m=j][n=co], A = hnT rows(j), B = Wv rows(co)
    f32x4 acc[16];
    #pragma unroll
    for (int t = 0; t < 16; ++t) acc[t] = (f32x4){0.f, 0.f, 0.f, 0.f};
    for (int kc = 0; kc < 8; ++kc) {
      bf16x8 hb = *(const bf16x8*)(hnT + ((size_t)b * NSP + i0 + w * 16 + li) * NCH + kc * 32 + qd * 8);
      #pragma unroll
      for (int ct = 0; ct < 16; ++ct) {
        bf16x8 wf = *(const bf16x8*)(W + (size_t)(ct * 16 + li) * NCH + kc * 32 + qd * 8);
        acc[ct] = __builtin_amdgcn_mfma_f32_16x16x32_bf16(hb, wf, acc[ct], 0, 0, 0);
      }
    }
    int jloc = w * 16 + qd * 4;                  // + r
    size_t base = (size_t)b * 1048576 + (size_t)((i0 + jloc) >> 5) * 8192;
    int r32 = jloc & 31;
    int jb = r32 >> 3;
    int ho = r32 & 7;                            // (qd&1)*4
    #pragma unroll
    for (int ct = 0; ct < 16; ++ct) {
      int co = ct * 16 + li;
      float bb = bv[co];
      int gran = co * 4 + (jb ^ ((co >> 1) & 3));
      union { bf16 h[4]; uint2 u; } pk;
      #pragma unroll
      for (int r = 0; r < 4; ++r) pk.h[r] = (bf16)(acc[ct][r] + bb);
      *(uint2*)(vS + base + gran * 8 + ho) = pk.u;
    }
    return;
  }

  // q/k: D[m=co][n=i], A = W rows(co), B = hnT rows(i)
  f32x4 acc[16];
  #pragma unroll
  for (int t = 0; t < 16; ++t) acc[t] = (f32x4){0.f, 0.f, 0.f, 0.f};
  for (int kc = 0; kc < 8; ++kc) {
    bf16x8 hb[4];
    #pragma unroll
    for (int nt = 0; nt < 4; ++nt)
      hb[nt] = *(const bf16x8*)(hnT + ((size_t)b * NSP + i0 + nt * 16 + li) * NCH + kc * 32 + qd * 8);
    #pragma unroll
    for (int mt = 0; mt < 4; ++mt) {
      bf16x8 wf = *(const bf16x8*)(W + (size_t)(w * 64 + mt * 16 + li) * NCH + kc * 32 + qd * 8);
      #pragma unroll
      for (int nt = 0; nt < 4; ++nt)
        acc[mt * 4 + nt] = __builtin_amdgcn_mfma_f32_16x16x32_bf16(wf, hb[nt], acc[mt * 4 + nt], 0, 0, 0);
    }
  }

  if (pass == 0) {
    bf16* out = qT + ((size_t)b * NSP + i0) * NCH;
    #pragma unroll
    for (int mt = 0; mt < 4; ++mt) {
      float bb[4];
      #pragma unroll
      for (int r = 0; r < 4; ++r) bb[r] = bq[w * 64 + mt * 16 + qd * 4 + r] * 0.0625f;
      #pragma unroll
      for (int nt = 0; nt < 4; ++nt) {
        union { bf16 h[4]; uint2 u; } pk;
        #pragma unroll
        for (int r = 0; r < 4; ++r) pk.h[r] = (bf16)(acc[mt * 4 + nt][r] + bb[r]);
        *(uint2*)(out + (size_t)(nt * 16 + li) * NCH + w * 64 + mt * 16 + qd * 4) = pk.u;
      }
    }
  } else {
    #pragma unroll
    for (int mt = 0; mt < 4; ++mt) {
      float bb[4];
      #pragma unroll
      for (int r = 0; r < 4; ++r) bb[r] = bk[w * 64 + mt * 16 + qd * 4 + r];
      int cb = w * 8 + mt * 2 + (qd >> 1);
      #pragma unroll
      for (int nt = 0; nt < 4; ++nt) {
        int jloc = nt * 16 + li;
        size_t base = (size_t)b * 1048576 + (size_t)((i0 + jloc) >> 5) * 8192;
        int r32 = jloc & 31;
        union { bf16 h[4]; uint2 u; } pk;
        #pragma unroll
        for (int r = 0; r < 4; ++r) pk.h[r] = (bf16)(acc[mt * 4 + nt][r] + bb[r]);
        *(uint2*)(kS + base + r32 * 256 + (cb ^ (r32 & 7)) * 8 + (qd & 1) * 4) = pk.u;
      }
    }
  }
}

// ---------------- k4: flash attention --------------------------------------
// 512 blocks = 32 i-tiles(128 rows) x 16 (b,js); 4 waves x 32 query rows.
// K double-buffered via global_load_lds (prefetch shadow = full compute);
// V prefetched in regs. (b,js) = blockIdx&15 pins working set to an XCD.
__global__ __launch_bounds__(256, 2) void k_attn(const bf16* __restrict__ qT,
    const bf16* __restrict__ kS, const bf16* __restrict__ vS,
    bf16* __restrict__ Op0, bf16* __restrict__ Op1, float* __restrict__ Lp) {
  __shared__ bf16 Kb[2][8192];    // 16 KB each, pre-swizzled granules
  __shared__ bf16 Vt[8192];       // 16 KB, pre-swizzled granules
  __shared__ bf16 Pt[4][32][36];  // per-wave P [i][j], pad 4

  const int bjs = blockIdx.x & 15;          // same (b,js) -> same XCD (%8)
  const int itb = blockIdx.x >> 4;          // 0..31
  const int b = bjs >> 1, js = bjs & 1;
  const int i0 = itb * 128;
  const int tid = threadIdx.x, w = tid >> 6, lane = tid & 63;
  const int li = lane & 15, qd = lane >> 4;

  const bf16* kS_b = kS + (size_t)b * 1048576 + (size_t)js * 524288;
  const bf16* vS_b = vS + (size_t)b * 1048576 + (size_t)js * 524288;

  bf16x8 qf[2][8];
  #pragma unroll
  for (int it = 0; it < 2; ++it) {
    const bf16* qp = qT + ((size_t)b * NSP + i0 + w * 32 + it * 16 + li) * NCH + qd * 8;
    #pragma unroll
    for (int kc = 0; kc < 8; ++kc) qf[it][kc] = *(const bf16x8*)(qp + kc * 32);
  }

  f32x4 Oa[2][16];
  #pragma unroll
  for (int it = 0; it < 2; ++it)
    #pragma unroll
    for (int t = 0; t < 16; ++t) Oa[it][t] = (f32x4){0.f, 0.f, 0.f, 0.f};
  float lacc[2][4] = {{0.f,0.f,0.f,0.f},{0.f,0.f,0.f,0.f}};

  // preamble: stage tile 0
  int4 Rv[4];
  #pragma unroll
  for (int p = 0; p < 4; ++p)
    glds16(kS_b + (size_t)(w * 256 + p * 64 + lane) * 8, &Kb[0][(w * 256 + p * 64) * 8]);
  #pragma unroll
  for (int p = 0; p < 4; ++p)
    Rv[p] = *(const int4*)(vS_b + (size_t)(p * 256 + tid) * 8);

  for (int jc = 0; jc < 64; ++jc) {
    const int cur = jc & 1;
    __syncthreads();                         // drains K(jc) glds + Rv(jc); prev reads done
    #pragma unroll
    for (int p = 0; p < 4; ++p)
      *(int4*)(&Vt[(p * 256 + tid) * 8]) = Rv[p];
    __syncthreads();                         // Vt visible

    {  // prefetch tile jc+1 (shadow = this iteration's compute)
      const int jn = (jc < 63) ? jc + 1 : 63;
      const bf16* kt = kS_b + (size_t)jn * 8192;
      const bf16* vt = vS_b + (size_t)jn * 8192;
      #pragma unroll
      for (int p = 0; p < 4; ++p)
        glds16(kt + (size_t)(w * 256 + p * 64 + lane) * 8, &Kb[cur ^ 1][(w * 256 + p * 64) * 8]);
      #pragma unroll
      for (int p = 0; p < 4; ++p)
        Rv[p] = *(const int4*)(vt + (size_t)(p * 256 + tid) * 8);
    }

    // S = Q K^T: 2 i-tiles x 2 j-tiles, each K-frag feeds 2 MFMAs
    const bf16* Kc = Kb[cur];
    f32x4 S[2][2];
    S[0][0] = (f32x4){0.f,0.f,0.f,0.f}; S[0][1] = (f32x4){0.f,0.f,0.f,0.f};
    S[1][0] = (f32x4){0.f,0.f,0.f,0.f}; S[1][1] = (f32x4){0.f,0.f,0.f,0.f};
    #pragma unroll
    for (int jt = 0; jt < 2; ++jt) {
      #pragma unroll
      for (int kc = 0; kc < 8; ++kc) {
        int pb = (kc * 4 + qd) ^ (li & 7);
        bf16x8 kf = *(const bf16x8*)(Kc + (jt * 16 + li) * 256 + pb * 8);
        S[0][jt] = __builtin_amdgcn_mfma_f32_16x16x32_bf16(qf[0][kc], kf, S[0][jt], 0, 0, 0);
        S[1][jt] = __builtin_amdgcn_mfma_f32_16x16x32_bf16(qf[1][kc], kf, S[1][jt], 0, 0, 0);
      }
    }

    // softmax numerator (shift-invariant; fixed -8 shift)
    #pragma unroll
    for (int it = 0; it < 2; ++it)
      #pragma unroll
      for (int jt = 0; jt < 2; ++jt)
        #pragma unroll
        for (int r = 0; r < 4; ++r) {
          float e = __expf(S[it][jt][r] - 8.f);
          lacc[it][r] += e;
          Pt[w][it * 16 + qd * 4 + r][jt * 16 + li] = (bf16)e;
        }

    // O += V P^T: each V-frag feeds 2 MFMAs
    bf16x8 pf[2];
    #pragma unroll
    for (int it = 0; it < 2; ++it)
      pf[it] = *(const bf16x8*)(&Pt[w][it * 16 + li][qd * 8]);
    #pragma unroll
    for (int ct = 0; ct < 16; ++ct) {
      int pbv = qd ^ ((li >> 1) & 3);
      bf16x8 vf = *(const bf16x8*)(&Vt[(ct * 16 + li) * 32 + pbv * 8]);
      Oa[0][ct] = __builtin_amdgcn_mfma_f32_16x16x32_bf16(vf, pf[0], Oa[0][ct], 0, 0, 0);
      Oa[1][ct] = __builtin_amdgcn_mfma_f32_16x16x32_bf16(vf, pf[1], Oa[1][ct], 0, 0, 0);
    }
  }

  float lrs[2][4], linv[2][4], lv[2];
  #pragma unroll
  for (int it = 0; it < 2; ++it) {
    #pragma unroll
    for (int r = 0; r < 4; ++r) {
      lrs[it][r] = red16_sum(lacc[it][r]);
      linv[it][r] = 1.f / lrs[it][r];
    }
    lv[it] = row2col(linv[it], li);
  }

  bf16* Op = js ? Op1 : Op0;
  #pragma unroll
  for (int it = 0; it < 2; ++it) {
    bf16* op = Op + ((size_t)b * NSP + i0 + w * 32 + it * 16 + li) * NCH;
    #pragma unroll
    for (int ct = 0; ct < 16; ++ct) {
      union { bf16 h[4]; uint2 u; } pk;
      pk.h[0] = (bf16)(Oa[it][ct][0] * lv[it]);
      pk.h[1] = (bf16)(Oa[it][ct][1] * lv[it]);
      pk.h[2] = (bf16)(Oa[it][ct][2] * lv[it]);
      pk.h[3] = (bf16)(Oa[it][ct][3] * lv[it]);
      *(uint2*)(op + ct * 16 + qd * 4) = pk.u;
    }
  }
  if (li == 0) {
    float* lp = Lp + js * 32768 + b * 4096 + i0 + w * 32;
    #pragma unroll
    for (int it = 0; it < 2; ++it)
      #pragma unroll
      for (int r = 0; r < 4; ++r) lp[it * 16 + qd * 4 + r] = lrs[it][r];
  }
}

// ---------------- k4b: combine the two j-split partials --------------------
__global__ __launch_bounds__(256) void k_combine(const bf16* __restrict__ Op0,
    const bf16* __restrict__ Op1, const float* __restrict__ Lp,
    bf16* __restrict__ aoT) {
  int g = blockIdx.x * 256 + threadIdx.x;      // 0..1048575
  int bi = g >> 5, cb = g & 31;
  float l0 = Lp[bi], l1 = Lp[32768 + bi];
  float inv = 1.f / (l0 + l1);
  float w0 = l0 * inv, w1 = l1 * inv;
  bf16x8 a = *(const bf16x8*)(Op0 + (size_t)bi * NCH + cb * 8);
  bf16x8 c = *(const bf16x8*)(Op1 + (size_t)bi * NCH + cb * 8);
  bf16x8 o;
  #pragma unroll
  for (int k = 0; k < 8; ++k) o[k] = (bf16)(w0 * (float)a[k] + w1 * (float)c[k]);
  *(bf16x8*)(aoT + (size_t)bi * NCH + cb * 8) = o;
}

// ---------------- k5: out = x + wo @ ao + bo, co-split x2 ------------------
__global__ __launch_bounds__(256, 4) void k_out(const bf16* __restrict__ aoT,
    const bf16* __restrict__ wo, const float* __restrict__ bo,
    const float* __restrict__ x, float* __restrict__ out) {
  const int b  = blockIdx.x >> 7;
  const int i0 = ((blockIdx.x >> 1) & 63) * 64;
  const int ch = blockIdx.x & 1;
  const int tid = threadIdx.x, w = tid >> 6, lane = tid & 63;
  const int li = lane & 15, qd = lane >> 4;
  const int cb0 = ch * 128 + w * 32;

  f32x4 acc[8];
  #pragma unroll
  for (int t = 0; t < 8; ++t) acc[t] = (f32x4){0.f, 0.f, 0.f, 0.f};
  for (int kc = 0; kc < 8; ++kc) {
    bf16x8 ab[4];
    #pragma unroll
    for (int nt = 0; nt < 4; ++nt)
      ab[nt] = *(const bf16x8*)(aoT + ((size_t)b * NSP + i0 + nt * 16 + li) * NCH + kc * 32 + qd * 8);
    #pragma unroll
    for (int mt = 0; mt < 2; ++mt) {
      bf16x8 wf = *(const bf16x8*)(wo + (size_t)(cb0 + mt * 16 + li) * NCH + kc * 32 + qd * 8);
      #pragma unroll
      for (int nt = 0; nt < 4; ++nt)
        acc[mt * 4 + nt] = __builtin_amdgcn_mfma_f32_16x16x32_bf16(wf, ab[nt], acc[mt * 4 + nt], 0, 0, 0);
    }
  }
  #pragma unroll
  for (int mt = 0; mt < 2; ++mt) {
    #pragma unroll
    for (int r = 0; r < 4; ++r) {
      int co = cb0 + mt * 16 + qd * 4 + r;
      float bb = bo[co];
      #pragma unroll
      for (int nt = 0; nt < 4; ++nt) {
        size_t idx = ((size_t)b * NCH + co) * NSP + i0 + nt * 16 + li;
        out[idx] = acc[mt * 4 + nt][r] + bb + x[idx];
      }
    }
  }
}

// ---------------- host ------------------------------------------------------
extern "C" void kernel_launch(void* const* d_in, const int* in_sizes, int n_in,
                              void* d_out, int out_size, void* d_ws, size_t ws_size,
                              hipStream_t stream) {
  (void)in_sizes; (void)n_in; (void)out_size; (void)ws_size;
  const float* x   = (const float*)d_in[0];
  const float* gsc = (const float*)d_in[1];
  const float* gbi = (const float*)d_in[2];
  const float* wq  = (const float*)d_in[3];
  const float* bq  = (const float*)d_in[4];
  const float* wk  = (const float*)d_in[5];
  const float* bk  = (const float*)d_in[6];
  const float* wv  = (const float*)d_in[7];
  const float* bv  = (const float*)d_in[8];
  const float* wo  = (const float*)d_in[9];
  const float* bo  = (const float*)d_in[10];

  char* ws = (char*)d_ws;
  const size_t MB16 = 16777216u;
  bf16*   wbf   = (bf16*)(ws);                         // 512 KB
  float*  stats = (float*)(ws + 524288);               // 512 B
  float2* part  = (float2*)(ws + 528384);              // 4 KB
  float*  Lp    = (float*)(ws + 655360);               // 256 KB
  bf16*   hnT   = (bf16*)(ws + (1u << 20));            // 16 MB; reused: Op0 -> aoT
  bf16*   qT    = (bf16*)(ws + (1u << 20) + 1 * MB16);
  bf16*   kS    = (bf16*)(ws + (1u << 20) + 2 * MB16); // swizzled K tiles
  bf16*   vS    = (bf16*)(ws + (1u << 20) + 3 * MB16); // swizzled V tiles
  bf16*   Op1   = (bf16*)(ws + (1u << 20) + 4 * MB16);
  bf16*   Op0   = hnT;   // hnT dead after k_qkv
  bf16*   aoT   = Op0;   // combine rewrites in place
  float*  out   = (float*)d_out;

  k_wconv   <<<1024, 256, 0, stream>>>(wq, wk, wv, wo, wbf);
  k_gnstats1<<< 512, 256, 0, stream>>>(x, part);
  k_gnstats2<<<   1,  64, 0, stream>>>(part, stats);
  k_gnapply <<<2048, 256, 0, stream>>>(x, stats, gsc, gbi, hnT);
  k_qkv     <<<1536, 256, 0, stream>>>(hnT, wbf, bq, bk, bv, qT, kS, vS);
  k_attn    <<< 512, 256, 0, stream>>>(qT, kS, vS, Op0, Op1, Lp);
  k_combine <<<4096, 256, 0, stream>>>(Op0, Op1, Lp, aoT);
  k_out     <<<1024, 256, 0, stream>>>(aoT, wbf + 3ull * 65536, bo, x, out);
}

// Round 4
// 456.377 us; speedup vs baseline: 1.5686x; 1.0364x over previous
//
#include <hip/hip_runtime.h>

typedef __bf16 bf16;
typedef __bf16 bf16x8 __attribute__((ext_vector_type(8)));
typedef float  f32x4  __attribute__((ext_vector_type(4)));

#define NSP 4096   // h*w
#define NCH 256    // channels
#define NB  8      // batch

// global(16B per lane) -> LDS at wave-uniform base + lane*16
static __device__ __forceinline__ void glds16(const bf16* g, bf16* l) {
  __builtin_amdgcn_global_load_lds(
      (const __attribute__((address_space(1))) unsigned int*)g,
      (__attribute__((address_space(3))) unsigned int*)l, 16, 0, 0);
}

// ---------------- k0: weights fp32 -> bf16 (wq gets 1/sqrt(c)=1/16) -------
__global__ __launch_bounds__(256) void k_wconv(
    const float* __restrict__ wq, const float* __restrict__ wk,
    const float* __restrict__ wv, const float* __restrict__ wo,
    bf16* __restrict__ wbf) {
  int g = blockIdx.x * 256 + threadIdx.x;
  int m = g >> 16, idx = g & 65535;
  const float* src = (m == 0) ? wq : (m == 1) ? wk : (m == 2) ? wv : wo;
  float sc = (m == 0) ? 0.0625f : 1.0f;
  wbf[g] = (bf16)(src[idx] * sc);
}

// ---------------- k1a: partial GN sums, 8 blocks per (b,g) ----------------
__global__ __launch_bounds__(256) void k_gnstats1(const float* __restrict__ x,
                                                  float2* __restrict__ part) {
  int blk = blockIdx.x;                         // 512 = 64 bg * 8 seg
  int bg = blk >> 3, seg = blk & 7;
  const float4* p = (const float4*)(x + (size_t)bg * 131072 + seg * 16384);
  float s = 0.f, s2 = 0.f;
  for (int i = threadIdx.x; i < 4096; i += 256) {
    float4 v = p[i];
    s  += v.x + v.y + v.z + v.w;
    s2 += v.x*v.x + v.y*v.y + v.z*v.z + v.w*v.w;
  }
  for (int off = 1; off < 64; off <<= 1) {
    s  += __shfl_xor(s, off);
    s2 += __shfl_xor(s2, off);
  }
  __shared__ float a1[4], a2[4];
  int w = threadIdx.x >> 6, lane = threadIdx.x & 63;
  if (lane == 0) { a1[w] = s; a2[w] = s2; }
  __syncthreads();
  if (threadIdx.x == 0)
    part[blk] = make_float2(a1[0]+a1[1]+a1[2]+a1[3], a2[0]+a2[1]+a2[2]+a2[3]);
}

// ---------------- k1b: finalize stats --------------------------------------
__global__ __launch_bounds__(64) void k_gnstats2(const float2* __restrict__ part,
                                                 float* __restrict__ stats) {
  int bg = threadIdx.x;                         // 64
  float s = 0.f, s2 = 0.f;
  #pragma unroll
  for (int k = 0; k < 8; ++k) {
    float2 v = part[bg * 8 + k];
    s += v.x; s2 += v.y;
  }
  float mean = s * (1.f / 131072.f);
  float var  = s2 * (1.f / 131072.f) - mean * mean;
  stats[bg * 2]     = mean;
  stats[bg * 2 + 1] = rsqrtf(var + 1e-6f);
}

// ---------------- k2: GN apply + transpose -> hnT[b][n][c] bf16 -----------
__global__ __launch_bounds__(256) void k_gnapply(const float* __restrict__ x,
    const float* __restrict__ stats, const float* __restrict__ gsc,
    const float* __restrict__ gbi, bf16* __restrict__ hnT) {
  __shared__ float T[64][65];
  int blk = blockIdx.x;                         // 2048
  int b = blk >> 8, ct = (blk >> 6) & 3, it = blk & 63;
  int tid = threadIdx.x;
  #pragma unroll 4
  for (int p = 0; p < 16; ++p) {
    int cc = p * 4 + (tid >> 6), ii = tid & 63;
    int c = ct * 64 + cc;
    float mean = stats[(b * 8 + (c >> 5)) * 2];
    float rstd = stats[(b * 8 + (c >> 5)) * 2 + 1];
    float v = x[((size_t)b * NCH + c) * NSP + it * 64 + ii];
    T[cc][ii] = (v - mean) * rstd * gsc[c] + gbi[c];
  }
  __syncthreads();
  #pragma unroll 4
  for (int p = 0; p < 16; ++p) {
    int ii = p * 4 + (tid >> 6), cc = tid & 63;
    hnT[((size_t)b * NSP + it * 64 + ii) * NCH + ct * 64 + cc] = (bf16)T[cc][ii];
  }
}

// ---------------- k3: QKV projection, one pass per block -------------------
// q: qT[b][i][c].  k: kS pre-swizzled K tiles (32 j x 256 c, granule
// pb = cb ^ (j&7), granule cb = 8 consecutive c).  v: vS pre-swizzled V
// tiles (256 c x 32 j); granule g of row c holds j in {4g+t} u {16+4g+t}
// (t=0..3), placed at pg = g ^ ((c>>1)&3). Linear image of k_attn's LDS.
__global__ __launch_bounds__(256, 4) void k_qkv(const bf16* __restrict__ hnT,
    const bf16* __restrict__ wbf, const float* __restrict__ bq,
    const float* __restrict__ bk, const float* __restrict__ bv,
    bf16* __restrict__ qT, bf16* __restrict__ kS, bf16* __restrict__ vS) {
  const int pass = blockIdx.x >> 9;             // 0:q 1:k 2:v
  const int rem  = blockIdx.x & 511;
  const int b  = rem >> 6;
  const int i0 = (rem & 63) * 64;
  const int tid = threadIdx.x, w = tid >> 6, lane = tid & 63;
  const int li = lane & 15, qd = lane >> 4;
  const bf16* W = wbf + (size_t)pass * 65536;

  if (pass == 2) {  // v: D[m=j][n=co], A = hnT rows(j), B = Wv rows(co)
    f32x4 acc[16];
    #pragma unroll
    for (int t = 0; t < 16; ++t) acc[t] = (f32x4){0.f, 0.f, 0.f, 0.f};
    for (int kc = 0; kc < 8; ++kc) {
      bf16x8 hb = *(const bf16x8*)(hnT + ((size_t)b * NSP + i0 + w * 16 + li) * NCH + kc * 32 + qd * 8);
      #pragma unroll
      for (int ct = 0; ct < 16; ++ct) {
        bf16x8 wf = *(const bf16x8*)(W + (size_t)(ct * 16 + li) * NCH + kc * 32 + qd * 8);
        acc[ct] = __builtin_amdgcn_mfma_f32_16x16x32_bf16(hb, wf, acc[ct], 0, 0, 0);
      }
    }
    int jloc = w * 16 + qd * 4;                  // + r over regs
    size_t base = (size_t)b * 1048576 + (size_t)((i0 + jloc) >> 5) * 8192;
    int j32 = jloc & 31;
    int g  = (j32 >> 2) & 3;                     // = qd
    int hi = j32 >> 4;                           // = w&1
    #pragma unroll
    for (int ct = 0; ct < 16; ++ct) {
      int co = ct * 16 + li;
      float bb = bv[co];
      int pg = g ^ ((co >> 1) & 3);
      union { bf16 h[4]; uint2 u; } pk;
      #pragma unroll
      for (int r = 0; r < 4; ++r) pk.h[r] = (bf16)(acc[ct][r] + bb);
      *(uint2*)(vS + base + (size_t)(co * 4 + pg) * 8 + hi * 4) = pk.u;
    }
    return;
  }

  // q/k: D[m=co][n=i], A = W rows(co), B = hnT rows(i)
  f32x4 acc[16];
  #pragma unroll
  for (int t = 0; t < 16; ++t) acc[t] = (f32x4){0.f, 0.f, 0.f, 0.f};
  for (int kc = 0; kc < 8; ++kc) {
    bf16x8 hb[4];
    #pragma unroll
    for (int nt = 0; nt < 4; ++nt)
      hb[nt] = *(const bf16x8*)(hnT + ((size_t)b * NSP + i0 + nt * 16 + li) * NCH + kc * 32 + qd * 8);
    #pragma unroll
    for (int mt = 0; mt < 4; ++mt) {
      bf16x8 wf = *(const bf16x8*)(W + (size_t)(w * 64 + mt * 16 + li) * NCH + kc * 32 + qd * 8);
      #pragma unroll
      for (int nt = 0; nt < 4; ++nt)
        acc[mt * 4 + nt] = __builtin_amdgcn_mfma_f32_16x16x32_bf16(wf, hb[nt], acc[mt * 4 + nt], 0, 0, 0);
    }
  }

  if (pass == 0) {
    bf16* out = qT + ((size_t)b * NSP + i0) * NCH;
    #pragma unroll
    for (int mt = 0; mt < 4; ++mt) {
      float bb[4];
      #pragma unroll
      for (int r = 0; r < 4; ++r) bb[r] = bq[w * 64 + mt * 16 + qd * 4 + r] * 0.0625f;
      #pragma unroll
      for (int nt = 0; nt < 4; ++nt) {
        union { bf16 h[4]; uint2 u; } pk;
        #pragma unroll
        for (int r = 0; r < 4; ++r) pk.h[r] = (bf16)(acc[mt * 4 + nt][r] + bb[r]);
        *(uint2*)(out + (size_t)(nt * 16 + li) * NCH + w * 64 + mt * 16 + qd * 4) = pk.u;
      }
    }
  } else {
    #pragma unroll
    for (int mt = 0; mt < 4; ++mt) {
      float bb[4];
      #pragma unroll
      for (int r = 0; r < 4; ++r) bb[r] = bk[w * 64 + mt * 16 + qd * 4 + r];
      int cb = w * 8 + mt * 2 + (qd >> 1);
      #pragma unroll
      for (int nt = 0; nt < 4; ++nt) {
        int jloc = nt * 16 + li;
        size_t base = (size_t)b * 1048576 + (size_t)((i0 + jloc) >> 5) * 8192;
        int r32 = jloc & 31;
        union { bf16 h[4]; uint2 u; } pk;
        #pragma unroll
        for (int r = 0; r < 4; ++r) pk.h[r] = (bf16)(acc[mt * 4 + nt][r] + bb[r]);
        *(uint2*)(kS + base + r32 * 256 + (cb ^ (r32 & 7)) * 8 + (qd & 1) * 4) = pk.u;
      }
    }
  }
}

// ---------------- k4: flash attention, transpose-free P --------------------
// 512 blocks = 32 i-tiles(128 rows) x 16 (b,js); 4 waves x 32 query rows.
// QK swapped (A=K,B=Q) -> S^T layout: lane holds S[i=li][j=jt*16+qd*4+r].
// exp+cvt in-register -> pf bf16x8 is directly the PV B-operand under the
// joint j-permutation matching vS granules {4g+t, 16+4g+t}. No P in LDS.
__global__ __launch_bounds__(256, 2) void k_attn(const bf16* __restrict__ qT,
    const bf16* __restrict__ kS, const bf16* __restrict__ vS,
    bf16* __restrict__ Op0, bf16* __restrict__ Op1, float* __restrict__ Lp) {
  __shared__ bf16 Kb[2][8192];    // 16 KB each, pre-swizzled granules
  __shared__ bf16 Vt[8192];       // 16 KB, pre-swizzled granules

  const int bjs = blockIdx.x & 15;          // same (b,js) -> same XCD (%8)
  const int itb = blockIdx.x >> 4;          // 0..31
  const int b = bjs >> 1, js = bjs & 1;
  const int i0 = itb * 128;
  const int tid = threadIdx.x, w = tid >> 6, lane = tid & 63;
  const int li = lane & 15, qd = lane >> 4;

  const bf16* kS_b = kS + (size_t)b * 1048576 + (size_t)js * 524288;
  const bf16* vS_b = vS + (size_t)b * 1048576 + (size_t)js * 524288;

  bf16x8 qf[2][8];
  #pragma unroll
  for (int it = 0; it < 2; ++it) {
    const bf16* qp = qT + ((size_t)b * NSP + i0 + w * 32 + it * 16 + li) * NCH + qd * 8;
    #pragma unroll
    for (int kc = 0; kc < 8; ++kc) qf[it][kc] = *(const bf16x8*)(qp + kc * 32);
  }

  f32x4 Oa[2][16];
  #pragma unroll
  for (int it = 0; it < 2; ++it)
    #pragma unroll
    for (int t = 0; t < 16; ++t) Oa[it][t] = (f32x4){0.f, 0.f, 0.f, 0.f};
  float lacc[2] = {0.f, 0.f};

  // preamble: stage tile 0
  int4 Rv[4];
  #pragma unroll
  for (int p = 0; p < 4; ++p)
    glds16(kS_b + (size_t)(w * 256 + p * 64 + lane) * 8, &Kb[0][(w * 256 + p * 64) * 8]);
  #pragma unroll
  for (int p = 0; p < 4; ++p)
    Rv[p] = *(const int4*)(vS_b + (size_t)(p * 256 + tid) * 8);

  const int pgv = qd ^ ((li >> 1) & 3);      // V granule swizzle (read side)

  for (int jc = 0; jc < 64; ++jc) {
    const int cur = jc & 1;
    __syncthreads();                         // drains K(jc) glds + Rv(jc); prev reads done
    #pragma unroll
    for (int p = 0; p < 4; ++p)
      *(int4*)(&Vt[(size_t)(p * 256 + tid) * 8]) = Rv[p];
    __syncthreads();                         // Vt visible

    {  // prefetch tile jc+1 (shadow = this iteration's compute)
      const int jn = (jc < 63) ? jc + 1 : 63;
      const bf16* kt = kS_b + (size_t)jn * 8192;
      const bf16* vt = vS_b + (size_t)jn * 8192;
      #pragma unroll
      for (int p = 0; p < 4; ++p)
        glds16(kt + (size_t)(w * 256 + p * 64 + lane) * 8, &Kb[cur ^ 1][(w * 256 + p * 64) * 8]);
      #pragma unroll
      for (int p = 0; p < 4; ++p)
        Rv[p] = *(const int4*)(vt + (size_t)(p * 256 + tid) * 8);
    }

    // S^T = (K Q^T): lane holds S[i=li][j=jt*16+qd*4+r]
    const bf16* Kc = Kb[cur];
    f32x4 S[2][2];
    S[0][0] = (f32x4){0.f,0.f,0.f,0.f}; S[0][1] = (f32x4){0.f,0.f,0.f,0.f};
    S[1][0] = (f32x4){0.f,0.f,0.f,0.f}; S[1][1] = (f32x4){0.f,0.f,0.f,0.f};
    #pragma unroll
    for (int jt = 0; jt < 2; ++jt) {
      #pragma unroll
      for (int kc = 0; kc < 8; ++kc) {
        int pb = (kc * 4 + qd) ^ (li & 7);
        bf16x8 kf = *(const bf16x8*)(Kc + (jt * 16 + li) * 256 + pb * 8);
        S[0][jt] = __builtin_amdgcn_mfma_f32_16x16x32_bf16(kf, qf[0][kc], S[0][jt], 0, 0, 0);
        S[1][jt] = __builtin_amdgcn_mfma_f32_16x16x32_bf16(kf, qf[1][kc], S[1][jt], 0, 0, 0);
      }
    }

    // P = exp(S-8) in-register; pf[it] is the PV B-operand (K=32, permuted j)
    bf16x8 pf[2];
    #pragma unroll
    for (int it = 0; it < 2; ++it)
      #pragma unroll
      for (int jt = 0; jt < 2; ++jt)
        #pragma unroll
        for (int r = 0; r < 4; ++r) {
          float e = __expf(S[it][jt][r] - 8.f);
          lacc[it] += e;
          pf[it][jt * 4 + r] = (bf16)e;
        }

    // O += V P^T: D[m=c][n=i]; one b128 V-frag per ct feeds both i-tiles
    #pragma unroll
    for (int ct = 0; ct < 16; ++ct) {
      bf16x8 vf = *(const bf16x8*)(&Vt[(size_t)(ct * 16 + li) * 32 + pgv * 8]);
      Oa[0][ct] = __builtin_amdgcn_mfma_f32_16x16x32_bf16(vf, pf[0], Oa[0][ct], 0, 0, 0);
      Oa[1][ct] = __builtin_amdgcn_mfma_f32_16x16x32_bf16(vf, pf[1], Oa[1][ct], 0, 0, 0);
    }
  }

  // epilogue: l is indexed by i=li -> just reduce across qd groups
  float lfull[2], linv[2];
  #pragma unroll
  for (int it = 0; it < 2; ++it) {
    float v = lacc[it];
    v += __shfl_xor(v, 16);
    v += __shfl_xor(v, 32);
    lfull[it] = v;
    linv[it] = 1.f / v;
  }

  bf16* Op = js ? Op1 : Op0;
  #pragma unroll
  for (int it = 0; it < 2; ++it) {
    bf16* op = Op + ((size_t)b * NSP + i0 + w * 32 + it * 16 + li) * NCH;
    #pragma unroll
    for (int ct = 0; ct < 16; ++ct) {
      union { bf16 h[4]; uint2 u; } pk;
      pk.h[0] = (bf16)(Oa[it][ct][0] * linv[it]);
      pk.h[1] = (bf16)(Oa[it][ct][1] * linv[it]);
      pk.h[2] = (bf16)(Oa[it][ct][2] * linv[it]);
      pk.h[3] = (bf16)(Oa[it][ct][3] * linv[it]);
      *(uint2*)(op + ct * 16 + qd * 4) = pk.u;
    }
  }
  if (qd == 0) {
    float* lp = Lp + js * 32768 + b * 4096 + i0 + w * 32;
    #pragma unroll
    for (int it = 0; it < 2; ++it) lp[it * 16 + li] = lfull[it];
  }
}

// ---------------- k5: out = x + wo @ blend(Op0,Op1) + bo -------------------
// combine fused: ab = (l0*Op0 + l1*Op1)/(l0+l1) per row i
__global__ __launch_bounds__(256, 4) void k_out(const bf16* __restrict__ Op0,
    const bf16* __restrict__ Op1, const float* __restrict__ Lp,
    const bf16* __restrict__ wo, const float* __restrict__ bo,
    const float* __restrict__ x, float* __restrict__ out) {
  const int b  = blockIdx.x >> 7;
  const int i0 = ((blockIdx.x >> 1) & 63) * 64;
  const int ch = blockIdx.x & 1;
  const int tid = threadIdx.x, w = tid >> 6, lane = tid & 63;
  const int li = lane & 15, qd = lane >> 4;
  const int cb0 = ch * 128 + w * 32;

  float w0[4], w1[4];
  #pragma unroll
  for (int nt = 0; nt < 4; ++nt) {
    int i = b * 4096 + i0 + nt * 16 + li;
    float l0 = Lp[i], l1 = Lp[32768 + i];
    float inv = 1.f / (l0 + l1);
    w0[nt] = l0 * inv; w1[nt] = l1 * inv;
  }

  f32x4 acc[8];
  #pragma unroll
  for (int t = 0; t < 8; ++t) acc[t] = (f32x4){0.f, 0.f, 0.f, 0.f};
  for (int kc = 0; kc < 8; ++kc) {
    bf16x8 ab[4];
    #pragma unroll
    for (int nt = 0; nt < 4; ++nt) {
      size_t off = ((size_t)b * NSP + i0 + nt * 16 + li) * NCH + kc * 32 + qd * 8;
      bf16x8 a0 = *(const bf16x8*)(Op0 + off);
      bf16x8 a1 = *(const bf16x8*)(Op1 + off);
      #pragma unroll
      for (int e = 0; e < 8; ++e)
        ab[nt][e] = (bf16)(w0[nt] * (float)a0[e] + w1[nt] * (float)a1[e]);
    }
    #pragma unroll
    for (int mt = 0; mt < 2; ++mt) {
      bf16x8 wf = *(const bf16x8*)(wo + (size_t)(cb0 + mt * 16 + li) * NCH + kc * 32 + qd * 8);
      #pragma unroll
      for (int nt = 0; nt < 4; ++nt)
        acc[mt * 4 + nt] = __builtin_amdgcn_mfma_f32_16x16x32_bf16(wf, ab[nt], acc[mt * 4 + nt], 0, 0, 0);
    }
  }
  #pragma unroll
  for (int mt = 0; mt < 2; ++mt) {
    #pragma unroll
    for (int r = 0; r < 4; ++r) {
      int co = cb0 + mt * 16 + qd * 4 + r;
      float bb = bo[co];
      #pragma unroll
      for (int nt = 0; nt < 4; ++nt) {
        size_t idx = ((size_t)b * NCH + co) * NSP + i0 + nt * 16 + li;
        out[idx] = acc[mt * 4 + nt][r] + bb + x[idx];
      }
    }
  }
}

// ---------------- host ------------------------------------------------------
extern "C" void kernel_launch(void* const* d_in, const int* in_sizes, int n_in,
                              void* d_out, int out_size, void* d_ws, size_t ws_size,
                              hipStream_t stream) {
  (void)in_sizes; (void)n_in; (void)out_size; (void)ws_size;
  const float* x   = (const float*)d_in[0];
  const float* gsc = (const float*)d_in[1];
  const float* gbi = (const float*)d_in[2];
  const float* wq  = (const float*)d_in[3];
  const float* bq  = (const float*)d_in[4];
  const float* wk  = (const float*)d_in[5];
  const float* bk  = (const float*)d_in[6];
  const float* wv  = (const float*)d_in[7];
  const float* bv  = (const float*)d_in[8];
  const float* wo  = (const float*)d_in[9];
  const float* bo  = (const float*)d_in[10];

  char* ws = (char*)d_ws;
  const size_t MB16 = 16777216u;
  bf16*   wbf   = (bf16*)(ws);                         // 512 KB
  float*  stats = (float*)(ws + 524288);               // 512 B
  float2* part  = (float2*)(ws + 528384);              // 4 KB
  float*  Lp    = (float*)(ws + 655360);               // 256 KB
  bf16*   hnT   = (bf16*)(ws + (1u << 20));            // 16 MB; reused as Op0
  bf16*   qT    = (bf16*)(ws + (1u << 20) + 1 * MB16);
  bf16*   kS    = (bf16*)(ws + (1u << 20) + 2 * MB16); // swizzled K tiles
  bf16*   vS    = (bf16*)(ws + (1u << 20) + 3 * MB16); // swizzled V tiles
  bf16*   Op1   = (bf16*)(ws + (1u << 20) + 4 * MB16);
  bf16*   Op0   = hnT;   // hnT dead after k_qkv
  float*  out   = (float*)d_out;

  k_wconv   <<<1024, 256, 0, stream>>>(wq, wk, wv, wo, wbf);
  k_gnstats1<<< 512, 256, 0, stream>>>(x, part);
  k_gnstats2<<<   1,  64, 0, stream>>>(part, stats);
  k_gnapply <<<2048, 256, 0, stream>>>(x, stats, gsc, gbi, hnT);
  k_qkv     <<<1536, 256, 0, stream>>>(hnT, wbf, bq, bk, bv, qT, kS, vS);
  k_attn    <<< 512, 256, 0, stream>>>(qT, kS, vS, Op0, Op1, Lp);
  k_out     <<<1024, 256, 0, stream>>>(Op0, Op1, Lp, wbf + 3ull * 65536, bo, x, out);
}